// Round 2
// baseline (946.022 us; speedup 1.0000x reference)
//
#include <hip/hip_runtime.h>
#include <hip/hip_bf16.h>

// GCN_large R2: 32x32x16-MFMA LDS-resident pipeline, all-b64 LDS writes.
// Layouts (per block, one batch item):
//   Xs [112][136] bf16  : X rows, cols 112..135 zeroed (K-pad for p1)
//   hT [256][120] bf16  : h feature-major [feat][node]
//   aB [128][264] bf16  : a node-major [node][feat]; rows 112..127 junk (never read)
// proj (form3): D[m=node][n=feat] = A(a rows) x B(W rows, global);
//               C written to hT[feat][node] as 4-contig b64 groups.
// agg  (form2): D[m=feat][n=node] = A(hT rows) x B(Xs rows);
//               a[i][f] = sum_j h[j][f]*X[i][j]  -> B[n=i][k=j] = X rows (no transpose).
//               C written to aB[node][feat] as b64 groups.

#define NODE 112
#define NBATCH 4096
#define SXS 136
#define SHT 120
#define SAB 264
#define XS_OFF 0
#define HT_OFF (112*SXS)               // 15232
#define AB_OFF (HT_OFF + 256*SHT)      // 45952
#define SMEM_BYTES ((AB_OFF + 128*SAB)*2)   // 159488 B

typedef float  f4v   __attribute__((ext_vector_type(4)));
typedef float  f16v  __attribute__((ext_vector_type(16)));
typedef __bf16 bf8v  __attribute__((ext_vector_type(8)));
typedef short  s8v   __attribute__((ext_vector_type(8)));

__device__ __forceinline__ unsigned short f2bf(float f) {
  union { float f; unsigned u; } v; v.f = f;
  unsigned r = v.u + 0x7FFFu + ((v.u >> 16) & 1u);   // RNE
  return (unsigned short)(r >> 16);
}
__device__ __forceinline__ float bf2f(unsigned short h) {
  union { unsigned u; float f; } v; v.u = ((unsigned)h) << 16; return v.f;
}
__device__ __forceinline__ unsigned pk2(float a, float b) {
  return (unsigned)f2bf(a) | ((unsigned)f2bf(b) << 16);
}
__device__ __forceinline__ bf8v ld_frag(const unsigned short* p) {
  s8v t = *(const s8v*)p;
  return __builtin_bit_cast(bf8v, t);
}
#define MFMA32(a,b,c) __builtin_amdgcn_mfma_f32_32x32x16_bf16((a),(b),(c),0,0,0)
#define MFMA16(a,b,c) __builtin_amdgcn_mfma_f32_16x16x32_bf16((a),(b),(c),0,0,0)

// ---------------- proj: hT[feat][node] = relu(A(a) . W^T + bias) ----------------
// NT = feat/32 tiles, KS = K/16, SA = stride of A rows (LDS).
template<int NT, int KS, int SA>
__device__ __forceinline__ void proj_phase32(
    const unsigned short* __restrict__ Wg, const float* __restrict__ bias,
    const unsigned short* aSrc, unsigned short* hDst, int wave, int lane)
{
  if (wave >= NT/2) return;
  const int K = KS*16;
  const int l31 = lane & 31, h32 = lane >> 5;
  const int l15 = lane & 15, q4 = lane >> 4;
  const int n0 = wave*2;

  // full m-tiles (nodes 0..95)
  f16v acc[2][3];
  #pragma unroll
  for (int n=0;n<2;n++)
    #pragma unroll
    for (int m=0;m<3;m++)
      #pragma unroll
      for (int r=0;r<16;r++) acc[n][m][r] = 0.f;

  const unsigned short* ar0 = aSrc + (0*32 + l31)*SA + h32*8;
  const unsigned short* ar1 = aSrc + (1*32 + l31)*SA + h32*8;
  const unsigned short* ar2 = aSrc + (2*32 + l31)*SA + h32*8;
  const unsigned short* br0 = Wg + ((n0+0)*32 + l31)*K + h32*8;
  const unsigned short* br1 = Wg + ((n0+1)*32 + l31)*K + h32*8;
  #pragma unroll
  for (int ks=0; ks<KS; ks++) {
    bf8v A0 = ld_frag(ar0 + ks*16);
    bf8v A1 = ld_frag(ar1 + ks*16);
    bf8v A2 = ld_frag(ar2 + ks*16);
    bf8v B0 = ld_frag(br0 + ks*16);
    bf8v B1 = ld_frag(br1 + ks*16);
    acc[0][0] = MFMA32(A0,B0,acc[0][0]);
    acc[0][1] = MFMA32(A1,B0,acc[0][1]);
    acc[0][2] = MFMA32(A2,B0,acc[0][2]);
    acc[1][0] = MFMA32(A0,B1,acc[1][0]);
    acc[1][1] = MFMA32(A1,B1,acc[1][1]);
    acc[1][2] = MFMA32(A2,B1,acc[1][2]);
  }

  // tail m-tile (nodes 96..111) via 16x16x32
  f4v acct[2][2];
  #pragma unroll
  for (int n=0;n<2;n++)
    #pragma unroll
    for (int s=0;s<2;s++) acct[n][s] = (f4v){0.f,0.f,0.f,0.f};
  const unsigned short* atr = aSrc + (96 + l15)*SA + q4*8;
  #pragma unroll
  for (int kc=0; kc<KS/2; kc++) {
    bf8v At = ld_frag(atr + kc*32);
    #pragma unroll
    for (int n=0;n<2;n++)
      #pragma unroll
      for (int s=0;s<2;s++) {
        bf8v Bt = ld_frag(Wg + ((n0+n)*32 + s*16 + l15)*K + kc*32 + q4*8);
        acct[n][s] = MFMA16(At, Bt, acct[n][s]);
      }
  }

  // epilogue: bias + relu + pack b64 into hT[feat][node]
  #pragma unroll
  for (int n=0;n<2;n++) {
    float bv = bias[(n0+n)*32 + l31];
    unsigned short* hrow = hDst + ((n0+n)*32 + l31)*SHT;
    #pragma unroll
    for (int m=0;m<3;m++)
      #pragma unroll
      for (int g=0;g<4;g++) {
        float v0 = acc[n][m][4*g+0] + bv; v0 = v0>0.f?v0:0.f;
        float v1 = acc[n][m][4*g+1] + bv; v1 = v1>0.f?v1:0.f;
        float v2 = acc[n][m][4*g+2] + bv; v2 = v2>0.f?v2:0.f;
        float v3 = acc[n][m][4*g+3] + bv; v3 = v3>0.f?v3:0.f;
        uint2 pv; pv.x = pk2(v0,v1); pv.y = pk2(v2,v3);
        *(uint2*)(hrow + m*32 + 8*g + 4*h32) = pv;
      }
  }
  #pragma unroll
  for (int n=0;n<2;n++)
    #pragma unroll
    for (int s=0;s<2;s++) {
      float bv = bias[(n0+n)*32 + s*16 + l15];
      float v0 = acct[n][s][0] + bv; v0 = v0>0.f?v0:0.f;
      float v1 = acct[n][s][1] + bv; v1 = v1>0.f?v1:0.f;
      float v2 = acct[n][s][2] + bv; v2 = v2>0.f?v2:0.f;
      float v3 = acct[n][s][3] + bv; v3 = v3>0.f?v3:0.f;
      uint2 pv; pv.x = pk2(v0,v1); pv.y = pk2(v2,v3);
      *(uint2*)(hDst + ((n0+n)*32 + s*16 + l15)*SHT + 96 + 4*q4) = pv;
    }
}

// ---------------- agg: aB[node][feat] = X . h  (K = 112 nodes) ----------------
template<int MT>
__device__ __forceinline__ void agg_phase32(
    const unsigned short* hSrc, const unsigned short* Xs_,
    unsigned short* aDst, int wave, int lane)
{
  if (wave >= MT/2) return;
  const int l31 = lane & 31, h32 = lane >> 5;
  const int m0 = wave*2;

  f16v acc[2][4];
  #pragma unroll
  for (int i=0;i<2;i++)
    #pragma unroll
    for (int t=0;t<4;t++)
      #pragma unroll
      for (int r=0;r<16;r++) acc[i][t][r] = 0.f;

  const unsigned short* ar0 = hSrc + ((m0+0)*32 + l31)*SHT + h32*8;
  const unsigned short* ar1 = hSrc + ((m0+1)*32 + l31)*SHT + h32*8;
  const unsigned short* br[4];
  #pragma unroll
  for (int t=0;t<4;t++) {
    int row = t*32 + l31; row = row > 111 ? 111 : row;   // clamp junk rows
    br[t] = Xs_ + row*SXS + h32*8;
  }
  #pragma unroll
  for (int ks=0; ks<7; ks++) {          // K = 112 exactly
    bf8v A0 = ld_frag(ar0 + ks*16);
    bf8v A1 = ld_frag(ar1 + ks*16);
    #pragma unroll
    for (int t=0;t<4;t++) {
      bf8v B = ld_frag(br[t] + ks*16);
      acc[0][t] = MFMA32(A0,B,acc[0][t]);
      acc[1][t] = MFMA32(A1,B,acc[1][t]);
    }
  }
  #pragma unroll
  for (int t=0;t<4;t++) {
    unsigned short* arow = aDst + (t*32 + l31)*SAB;
    #pragma unroll
    for (int i=0;i<2;i++)
      #pragma unroll
      for (int g=0;g<4;g++) {
        uint2 pv;
        pv.x = pk2(acc[i][t][4*g+0], acc[i][t][4*g+1]);
        pv.y = pk2(acc[i][t][4*g+2], acc[i][t][4*g+3]);
        *(uint2*)(arow + (m0+i)*32 + 8*g + 4*h32) = pv;
      }
  }
}

__global__ void prep_weights(const float* __restrict__ W1, const float* __restrict__ W2,
                             const float* __restrict__ W3, const float* __restrict__ W4,
                             unsigned short* __restrict__ o)
{
  int i = blockIdx.x*256 + threadIdx.x;
  if (i < 32768) {                       // W1p [256][128], K zero-padded
    int r = i >> 7, c = i & 127;
    o[i] = (c < NODE) ? f2bf(W1[r*NODE + c]) : (unsigned short)0;
  } else if (i < 98304) {                // W2 [256][256]
    o[i] = f2bf(W2[i - 32768]);
  } else if (i < 131072) {               // W3 [128][256]
    o[i] = f2bf(W3[i - 98304]);
  } else if (i < 139264) {               // W4 [64][128]
    o[i] = f2bf(W4[i - 131072]);
  }
}

__global__ void __launch_bounds__(256, 1) gcn_kernel(
    const float* __restrict__ x, const unsigned short* __restrict__ wsp,
    const float* __restrict__ b1, const float* __restrict__ b2,
    const float* __restrict__ b3, const float* __restrict__ b4,
    const float* __restrict__ W5, const float* __restrict__ b5,
    const float* __restrict__ Wf, const float* __restrict__ bfc,
    float* __restrict__ out)
{
  extern __shared__ unsigned short smem[];
  unsigned short* Xs = smem + XS_OFF;
  unsigned short* hT = smem + HT_OFF;
  unsigned short* aB = smem + AB_OFF;

  const int tid  = threadIdx.x;
  const int wave = tid >> 6;
  const int lane = tid & 63;

  // zero Xs pad cols 112..135
  for (int i = tid; i < 112*6; i += 256) {
    int r = i/6, g = i - r*6;
    uint2 z; z.x = 0u; z.y = 0u;
    *(uint2*)(Xs + r*SXS + 112 + g*4) = z;
  }
  // stage X: fp32 global -> bf16 LDS (b64 packed writes)
  {
    const float4* x4 = (const float4*)(x + (size_t)blockIdx.x * (NODE*NODE));
    for (int i = tid; i < (NODE*NODE/4); i += 256) {
      float4 v = x4[i];
      int r = i / 28, c4 = (i - r*28) * 4;
      uint2 pv; pv.x = pk2(v.x, v.y); pv.y = pk2(v.z, v.w);
      *(uint2*)(Xs + r*SXS + c4) = pv;
    }
  }
  __syncthreads();

  proj_phase32<8, 8, SXS>(wsp,          b1, Xs, hT, wave, lane);  // h1 [256]
  __syncthreads();
  agg_phase32<8>(hT, Xs, aB, wave, lane);                          // a2 [256]
  __syncthreads();
  proj_phase32<8, 16, SAB>(wsp + 32768, b2, aB, hT, wave, lane);   // h2 [256]
  __syncthreads();
  agg_phase32<8>(hT, Xs, aB, wave, lane);                          // a3 [256]
  __syncthreads();
  proj_phase32<4, 16, SAB>(wsp + 98304, b3, aB, hT, wave, lane);   // h3 [128]
  __syncthreads();
  agg_phase32<4>(hT, Xs, aB, wave, lane);                          // a4 [128]
  __syncthreads();
  proj_phase32<2, 8, SAB>(wsp + 131072, b4, aB, hT, wave, lane);   // h4 [64]
  __syncthreads();
  agg_phase32<2>(hT, Xs, aB, wave, lane);                          // a5 [64]
  __syncthreads();

  // final: h5[n] = relu(b5 + a5[n][:].W5); out = bf + sum_n h5[n]*Wf[n]
  float partial = 0.f;
  if (tid < NODE) {
    const unsigned short* row = aB + tid*SAB;
    float s = 0.f;
    #pragma unroll
    for (int k4 = 0; k4 < 16; k4++) {
      uint2 u = *(const uint2*)(row + k4*4);
      s += bf2f((unsigned short)(u.x & 0xFFFF))        * W5[k4*4+0];
      s += bf2f((unsigned short)(u.x >> 16))           * W5[k4*4+1];
      s += bf2f((unsigned short)(u.y & 0xFFFF))        * W5[k4*4+2];
      s += bf2f((unsigned short)(u.y >> 16))           * W5[k4*4+3];
    }
    s += b5[0];
    s = s > 0.f ? s : 0.f;
    partial = s * Wf[tid];
  }
  float* red = (float*)Xs;               // Xs dead after a5
  red[tid] = partial;
  __syncthreads();
  if (tid == 0) {
    float s = bfc[0];
    #pragma unroll
    for (int i = 0; i < NODE; i++) s += red[i];
    out[blockIdx.x] = s;
  }
}

extern "C" void kernel_launch(void* const* d_in, const int* in_sizes, int n_in,
                              void* d_out, int out_size, void* d_ws, size_t ws_size,
                              hipStream_t stream) {
  const float* x   = (const float*)d_in[0];
  const float* W1  = (const float*)d_in[1];
  const float* b1  = (const float*)d_in[2];
  const float* W2  = (const float*)d_in[3];
  const float* b2  = (const float*)d_in[4];
  const float* W3  = (const float*)d_in[5];
  const float* b3  = (const float*)d_in[6];
  const float* W4  = (const float*)d_in[7];
  const float* b4  = (const float*)d_in[8];
  const float* W5  = (const float*)d_in[9];
  const float* b5  = (const float*)d_in[10];
  const float* Wf  = (const float*)d_in[11];
  const float* bfc = (const float*)d_in[12];
  unsigned short* wsp = (unsigned short*)d_ws;
  float* out = (float*)d_out;

  prep_weights<<<544, 256, 0, stream>>>(W1, W2, W3, W4, wsp);

  (void)hipFuncSetAttribute((const void*)gcn_kernel,
                            hipFuncAttributeMaxDynamicSharedMemorySize, SMEM_BYTES);
  gcn_kernel<<<NBATCH, 256, SMEM_BYTES, stream>>>(x, wsp, b1, b2, b3, b4,
                                                  W5, b5, Wf, bfc, out);
}

// Round 3
// 698.090 us; speedup vs baseline: 1.3552x; 1.3552x over previous
//
#include <hip/hip_runtime.h>
#include <hip/hip_bf16.h>

// GCN_large R3: 32x32x16 MFMA pipeline, 512 thr / 8 waves, every phase uses
// all 8 waves via 2-D tile split. Layouts:
//   Xs [112][136] bf16 : X rows, cols 112..127 zeroed (K-pad)
//   hT [256][136] bf16 : h feature-major [feat][node], cols 112..127 zeroed
//   aB [112][264] bf16 : a node-major [node][feat]
// proj: D[m=node][n=feat] = A(a rows, LDS) x B(W rows, global)
// agg : D[m=feat][n=node] = A(hT rows) x B(Xs rows), K=112 exact (MFMA32)
// node-tail (96..111) via 16x16x32 with K zero-padded to 128.

#define NODE 112
#define NBATCH 4096
#define SXS 136
#define SHT 136
#define SAB 264
#define HT_OFF (112*SXS)                 // 15232
#define AB_OFF (HT_OFF + 256*SHT)        // 50048
#define SMEM_BYTES ((AB_OFF + 112*SAB)*2)  // 159232 B

typedef float  f4v   __attribute__((ext_vector_type(4)));
typedef float  f16v  __attribute__((ext_vector_type(16)));
typedef __bf16 bf8v  __attribute__((ext_vector_type(8)));
typedef short  s8v   __attribute__((ext_vector_type(8)));
typedef unsigned short ushort_t;

__device__ __forceinline__ ushort_t f2bf(float f) {
  union { float f; unsigned u; } v; v.f = f;
  unsigned r = v.u + 0x7FFFu + ((v.u >> 16) & 1u);   // RNE
  return (ushort_t)(r >> 16);
}
__device__ __forceinline__ float bf2f(ushort_t h) {
  union { unsigned u; float f; } v; v.u = ((unsigned)h) << 16; return v.f;
}
__device__ __forceinline__ unsigned pk2(float a, float b) {
  return (unsigned)f2bf(a) | ((unsigned)f2bf(b) << 16);
}
__device__ __forceinline__ bf8v ld_frag(const ushort_t* p) {
  s8v t = *(const s8v*)p;
  return __builtin_bit_cast(bf8v, t);
}
#define MFMA32(a,b,c) __builtin_amdgcn_mfma_f32_32x32x16_bf16((a),(b),(c),0,0,0)
#define MFMA16(a,b,c) __builtin_amdgcn_mfma_f32_16x16x32_bf16((a),(b),(c),0,0,0)

// proj: hT[feat][node] = relu(a . W^T + bias). One wave: n-tile `ntile`,
// NMT main 32-node tiles from `mstart`, optional 16-node tail (96..111).
template<int KS, int KC, int SA_, int NMT, bool TAIL>
__device__ __forceinline__ void proj_part(
    const ushort_t* aSrc, const ushort_t* __restrict__ Wg, int WK,
    const float* __restrict__ bias, ushort_t* hDst,
    int ntile, int mstart, int lane)
{
  const int l31 = lane & 31, h32 = lane >> 5;
  const int l15 = lane & 15, q4 = lane >> 4;

  f16v acc[NMT > 0 ? NMT : 1];
  if (NMT > 0) {
    #pragma unroll
    for (int m=0;m<NMT;m++)
      #pragma unroll
      for (int r=0;r<16;r++) acc[m][r] = 0.f;
    const ushort_t* aP = aSrc + (mstart*32 + l31)*SA_ + h32*8;
    const ushort_t* bP = Wg + (ntile*32 + l31)*WK + h32*8;
    #pragma unroll
    for (int ks=0; ks<KS; ks++) {
      bf8v B = ld_frag(bP + ks*16);
      #pragma unroll
      for (int m=0;m<NMT;m++)
        acc[m] = MFMA32(ld_frag(aP + m*32*SA_ + ks*16), B, acc[m]);
    }
  }
  f4v at0, at1;
  if (TAIL) {
    at0 = (f4v){0.f,0.f,0.f,0.f}; at1 = (f4v){0.f,0.f,0.f,0.f};
    const ushort_t* aT  = aSrc + (96 + l15)*SA_ + q4*8;
    const ushort_t* bT0 = Wg + (ntile*32 + l15)*WK + q4*8;
    const ushort_t* bT1 = bT0 + 16*WK;
    #pragma unroll
    for (int kc=0; kc<KC; kc++) {
      bf8v At = ld_frag(aT + kc*32);
      at0 = MFMA16(At, ld_frag(bT0 + kc*32), at0);
      at1 = MFMA16(At, ld_frag(bT1 + kc*32), at1);
    }
  }
  if (NMT > 0) {
    float bv = bias[ntile*32 + l31];
    ushort_t* hrow = hDst + (ntile*32 + l31)*SHT;
    #pragma unroll
    for (int m=0;m<NMT;m++)
      #pragma unroll
      for (int g=0;g<4;g++) {
        float v0=acc[m][4*g+0]+bv; v0=v0>0.f?v0:0.f;
        float v1=acc[m][4*g+1]+bv; v1=v1>0.f?v1:0.f;
        float v2=acc[m][4*g+2]+bv; v2=v2>0.f?v2:0.f;
        float v3=acc[m][4*g+3]+bv; v3=v3>0.f?v3:0.f;
        uint2 pv; pv.x = pk2(v0,v1); pv.y = pk2(v2,v3);
        *(uint2*)(hrow + (mstart+m)*32 + 8*g + 4*h32) = pv;
      }
  }
  if (TAIL) {
    #pragma unroll
    for (int s=0;s<2;s++) {
      const f4v& a = s ? at1 : at0;
      float bv = bias[ntile*32 + s*16 + l15];
      float v0=a[0]+bv; v0=v0>0.f?v0:0.f;
      float v1=a[1]+bv; v1=v1>0.f?v1:0.f;
      float v2=a[2]+bv; v2=v2>0.f?v2:0.f;
      float v3=a[3]+bv; v3=v3>0.f?v3:0.f;
      uint2 pv; pv.x = pk2(v0,v1); pv.y = pk2(v2,v3);
      *(uint2*)(hDst + (ntile*32 + s*16 + l15)*SHT + 96 + 4*q4) = pv;
    }
  }
}

// agg: aB[node][feat] = X . h. One wave: feat-tile `mt`, NNT main node-tiles
// from `nstart`, optional node tail (96..111).
template<int NNT, bool TAIL>
__device__ __forceinline__ void agg_part(
    const ushort_t* hS, const ushort_t* Xs_, ushort_t* aDst,
    int mt, int nstart, int lane)
{
  const int l31 = lane & 31, h32 = lane >> 5;
  const int l15 = lane & 15, q4 = lane >> 4;

  f16v acc[NNT > 0 ? NNT : 1];
  if (NNT > 0) {
    #pragma unroll
    for (int n=0;n<NNT;n++)
      #pragma unroll
      for (int r=0;r<16;r++) acc[n][r] = 0.f;
    const ushort_t* aP = hS + (mt*32 + l31)*SHT + h32*8;
    const ushort_t* bP = Xs_ + (nstart*32 + l31)*SXS + h32*8;
    #pragma unroll
    for (int ks=0; ks<7; ks++) {              // K = 112 exact
      bf8v A = ld_frag(aP + ks*16);
      #pragma unroll
      for (int n=0;n<NNT;n++)
        acc[n] = MFMA32(A, ld_frag(bP + n*32*SXS + ks*16), acc[n]);
    }
  }
  f4v at0, at1;
  if (TAIL) {
    at0 = (f4v){0.f,0.f,0.f,0.f}; at1 = (f4v){0.f,0.f,0.f,0.f};
    const ushort_t* bT  = Xs_ + (96 + l15)*SXS + q4*8;
    const ushort_t* aT0 = hS + (mt*32 + l15)*SHT + q4*8;
    const ushort_t* aT1 = aT0 + 16*SHT;
    #pragma unroll
    for (int kc=0; kc<4; kc++) {              // K padded to 128 (zeros)
      bf8v Bt = ld_frag(bT + kc*32);
      at0 = MFMA16(ld_frag(aT0 + kc*32), Bt, at0);
      at1 = MFMA16(ld_frag(aT1 + kc*32), Bt, at1);
    }
  }
  if (NNT > 0) {
    #pragma unroll
    for (int n=0;n<NNT;n++) {
      ushort_t* arow = aDst + ((nstart+n)*32 + l31)*SAB;
      #pragma unroll
      for (int g=0;g<4;g++) {
        uint2 pv;
        pv.x = pk2(acc[n][4*g+0], acc[n][4*g+1]);
        pv.y = pk2(acc[n][4*g+2], acc[n][4*g+3]);
        *(uint2*)(arow + mt*32 + 8*g + 4*h32) = pv;
      }
    }
  }
  if (TAIL) {
    ushort_t* arow = aDst + (96 + l15)*SAB;
    #pragma unroll
    for (int s=0;s<2;s++) {
      const f4v& a = s ? at1 : at0;
      uint2 pv; pv.x = pk2(a[0],a[1]); pv.y = pk2(a[2],a[3]);
      *(uint2*)(arow + mt*32 + s*16 + 4*q4) = pv;
    }
  }
}

__global__ void prep_weights(const float* __restrict__ W1, const float* __restrict__ W2,
                             const float* __restrict__ W3, const float* __restrict__ W4,
                             ushort_t* __restrict__ o)
{
  int i = blockIdx.x*256 + threadIdx.x;
  if (i < 32768) {                       // W1p [256][128], K zero-padded
    int r = i >> 7, c = i & 127;
    o[i] = (c < NODE) ? f2bf(W1[r*NODE + c]) : (ushort_t)0;
  } else if (i < 98304) {                // W2 [256][256]
    o[i] = f2bf(W2[i - 32768]);
  } else if (i < 131072) {               // W3 [128][256]
    o[i] = f2bf(W3[i - 98304]);
  } else if (i < 139264) {               // W4 [64][128]
    o[i] = f2bf(W4[i - 131072]);
  }
}

__global__ void __launch_bounds__(512, 2) gcn_kernel(
    const float* __restrict__ x, const ushort_t* __restrict__ wsp,
    const float* __restrict__ b1, const float* __restrict__ b2,
    const float* __restrict__ b3, const float* __restrict__ b4,
    const float* __restrict__ W5, const float* __restrict__ b5,
    const float* __restrict__ Wf, const float* __restrict__ bfc,
    float* __restrict__ out)
{
  extern __shared__ ushort_t smem[];
  ushort_t* Xs = smem;
  ushort_t* hT = smem + HT_OFF;
  ushort_t* aB = smem + AB_OFF;

  const int tid  = threadIdx.x;
  const int w    = tid >> 6;
  const int lane = tid & 63;

  // zero K-pad cols 112..127 of Xs and hT (read by MFMA16 tails)
  for (int i = tid; i < 112*4; i += 512) {
    int r = i >> 2, g = i & 3;
    *(uint2*)(Xs + r*SXS + 112 + g*4) = make_uint2(0u, 0u);
  }
  for (int i = tid; i < 256*4; i += 512) {
    int r = i >> 2, g = i & 3;
    *(uint2*)(hT + r*SHT + 112 + g*4) = make_uint2(0u, 0u);
  }
  // stage X: fp32 global -> bf16 LDS (b64 packed writes)
  {
    const float4* x4 = (const float4*)(x + (size_t)blockIdx.x * (NODE*NODE));
    for (int i = tid; i < (NODE*NODE/4); i += 512) {
      float4 v = x4[i];
      int r = i / 28, c4 = (i - r*28) * 4;
      uint2 pv; pv.x = pk2(v.x, v.y); pv.y = pk2(v.z, v.w);
      *(uint2*)(Xs + r*SXS + c4) = pv;
    }
  }
  __syncthreads();

  // p1: F=256, K=112 (tail Kpad=128); wave = n-tile
  proj_part<7,4,SXS,3,true>(Xs, wsp, 128, b1, hT, w, 0, lane);
  __syncthreads();
  // a2: F=256; wave = feat-tile
  agg_part<3,true>(hT, Xs, aB, w, 0, lane);
  __syncthreads();
  // p2: F=256, K=256
  proj_part<16,8,SAB,3,true>(aB, wsp + 32768, 256, b2, hT, w, 0, lane);
  __syncthreads();
  // a3: F=256
  agg_part<3,true>(hT, Xs, aB, w, 0, lane);
  __syncthreads();
  // p3: F=128, K=256; wave = (n-tile, m-half)
  if ((w >> 2) == 0) proj_part<16,8,SAB,2,false>(aB, wsp + 98304, 256, b3, hT, w & 3, 0, lane);
  else               proj_part<16,8,SAB,1,true >(aB, wsp + 98304, 256, b3, hT, w & 3, 2, lane);
  __syncthreads();
  // a4: F=128; wave = (feat-tile, n-half)
  if ((w >> 2) == 0) agg_part<2,false>(hT, Xs, aB, w & 3, 0, lane);
  else               agg_part<1,true >(hT, Xs, aB, w & 3, 2, lane);
  __syncthreads();
  // p4: F=64, K=128; wave = (n-tile, m-quarter)
  { int nt = w & 1, mq = w >> 1;
    if (mq < 3) proj_part<8,4,SAB,1,false>(aB, wsp + 131072, 128, b4, hT, nt, mq, lane);
    else        proj_part<8,4,SAB,0,true >(aB, wsp + 131072, 128, b4, hT, nt, 0, lane);
  }
  __syncthreads();
  // a5: F=64; wave = (feat-tile, n-quarter)
  { int mt = w & 1, nq = w >> 1;
    if (nq < 3) agg_part<1,false>(hT, Xs, aB, mt, nq, lane);
    else        agg_part<0,true >(hT, Xs, aB, mt, 0, lane);
  }
  __syncthreads();

  // final: h5[n] = relu(b5 + a5[n][:].W5); out = bf + sum_n h5[n]*Wf[n]
  float partial = 0.f;
  if (tid < NODE) {
    const ushort_t* row = aB + tid*SAB;
    float s = 0.f;
    #pragma unroll
    for (int k4 = 0; k4 < 16; k4++) {
      uint2 u = *(const uint2*)(row + k4*4);
      s += bf2f((ushort_t)(u.x & 0xFFFF)) * W5[k4*4+0];
      s += bf2f((ushort_t)(u.x >> 16))    * W5[k4*4+1];
      s += bf2f((ushort_t)(u.y & 0xFFFF)) * W5[k4*4+2];
      s += bf2f((ushort_t)(u.y >> 16))    * W5[k4*4+3];
    }
    s += b5[0];
    s = s > 0.f ? s : 0.f;
    partial = s * Wf[tid];
  }
  float* red = (float*)Xs;               // Xs dead after a5
  red[tid] = partial;
  __syncthreads();
  if (tid == 0) {
    float s = bfc[0];
    #pragma unroll
    for (int i = 0; i < NODE; i++) s += red[i];
    out[blockIdx.x] = s;
  }
}

extern "C" void kernel_launch(void* const* d_in, const int* in_sizes, int n_in,
                              void* d_out, int out_size, void* d_ws, size_t ws_size,
                              hipStream_t stream) {
  const float* x   = (const float*)d_in[0];
  const float* W1  = (const float*)d_in[1];
  const float* b1  = (const float*)d_in[2];
  const float* W2  = (const float*)d_in[3];
  const float* b2  = (const float*)d_in[4];
  const float* W3  = (const float*)d_in[5];
  const float* b3  = (const float*)d_in[6];
  const float* W4  = (const float*)d_in[7];
  const float* b4  = (const float*)d_in[8];
  const float* W5  = (const float*)d_in[9];
  const float* b5  = (const float*)d_in[10];
  const float* Wf  = (const float*)d_in[11];
  const float* bfc = (const float*)d_in[12];
  ushort_t* wsp = (ushort_t*)d_ws;
  float* out = (float*)d_out;

  prep_weights<<<544, 256, 0, stream>>>(W1, W2, W3, W4, wsp);

  (void)hipFuncSetAttribute((const void*)gcn_kernel,
                            hipFuncAttributeMaxDynamicSharedMemorySize, SMEM_BYTES);
  gcn_kernel<<<NBATCH, 512, SMEM_BYTES, stream>>>(x, wsp, b1, b2, b3, b4,
                                                  W5, b5, Wf, bfc, out);
}

// Round 4
// 651.592 us; speedup vs baseline: 1.4519x; 1.0714x over previous
//
#include <hip/hip_runtime.h>
#include <hip/hip_bf16.h>

// GCN_large R4: fused proj->agg phases (same-wave dependency, no barrier),
// 5 barriers instead of 9. 512 thr / 8 waves, 32x32x16 MFMA main tiles,
// 16x16x32 node-tail. Layouts:
//   Xs [112][136] bf16 : X rows, cols 112..127 zeroed (K-pad)
//   hT [256][136] bf16 : h feature-major [feat][node], cols 112..127 zeroed
//   aB [112][264] bf16 : a node-major [node][feat]
// proj: D[m=node][n=feat] = A(a rows, LDS) x B(W rows, global)
// agg : D[m=feat][n=node] = A(hT rows) x B(Xs rows), K=112 exact
// Fusion invariant: proj wave n writes hT rows [32n,32n+32); agg wave mt=n
// reads only those rows + static Xs -> no inter-wave dep -> no barrier.

#define NODE 112
#define NBATCH 4096
#define SXS 136
#define SHT 136
#define SAB 264
#define HT_OFF (112*SXS)                 // 15232
#define AB_OFF (HT_OFF + 256*SHT)        // 50048
#define SMEM_BYTES ((AB_OFF + 112*SAB)*2)  // 159232 B

typedef float  f4v   __attribute__((ext_vector_type(4)));
typedef float  f16v  __attribute__((ext_vector_type(16)));
typedef __bf16 bf8v  __attribute__((ext_vector_type(8)));
typedef short  s8v   __attribute__((ext_vector_type(8)));
typedef unsigned short ushort_t;

__device__ __forceinline__ ushort_t f2bf(float f) {
  union { float f; unsigned u; } v; v.f = f;
  unsigned r = v.u + 0x7FFFu + ((v.u >> 16) & 1u);   // RNE
  return (ushort_t)(r >> 16);
}
__device__ __forceinline__ float bf2f(ushort_t h) {
  union { unsigned u; float f; } v; v.u = ((unsigned)h) << 16; return v.f;
}
__device__ __forceinline__ unsigned pk2(float a, float b) {
  return (unsigned)f2bf(a) | ((unsigned)f2bf(b) << 16);
}
__device__ __forceinline__ bf8v ld_frag(const ushort_t* p) {
  s8v t = *(const s8v*)p;
  return __builtin_bit_cast(bf8v, t);
}
#define MFMA32(a,b,c) __builtin_amdgcn_mfma_f32_32x32x16_bf16((a),(b),(c),0,0,0)
#define MFMA16(a,b,c) __builtin_amdgcn_mfma_f32_16x16x32_bf16((a),(b),(c),0,0,0)

// proj: hT[feat][node] = relu(a . W^T + bias). Wave handles n-tile `ntile`,
// all nodes: NMT=3 main 32-node tiles + 16-node tail (96..111).
template<int KS, int KC, int SA_>
__device__ __forceinline__ void proj_full(
    const ushort_t* aSrc, const ushort_t* __restrict__ Wg, int WK,
    const float* __restrict__ bias, ushort_t* hDst, int ntile, int lane)
{
  const int l31 = lane & 31, h32 = lane >> 5;
  const int l15 = lane & 15, q4 = lane >> 4;

  f16v acc[3];
  #pragma unroll
  for (int m=0;m<3;m++)
    #pragma unroll
    for (int r=0;r<16;r++) acc[m][r] = 0.f;
  const ushort_t* aP = aSrc + l31*SA_ + h32*8;
  const ushort_t* bP = Wg + (ntile*32 + l31)*WK + h32*8;
  #pragma unroll
  for (int ks=0; ks<KS; ks++) {
    bf8v B = ld_frag(bP + ks*16);
    #pragma unroll
    for (int m=0;m<3;m++)
      acc[m] = MFMA32(ld_frag(aP + m*32*SA_ + ks*16), B, acc[m]);
  }
  // node tail 96..111 via 16x16x32 (K zero-padded)
  f4v at0 = (f4v){0.f,0.f,0.f,0.f}, at1 = (f4v){0.f,0.f,0.f,0.f};
  {
    const ushort_t* aT  = aSrc + (96 + l15)*SA_ + q4*8;
    const ushort_t* bT0 = Wg + (ntile*32 + l15)*WK + q4*8;
    const ushort_t* bT1 = bT0 + 16*WK;
    #pragma unroll
    for (int kc=0; kc<KC; kc++) {
      bf8v At = ld_frag(aT + kc*32);
      at0 = MFMA16(At, ld_frag(bT0 + kc*32), at0);
      at1 = MFMA16(At, ld_frag(bT1 + kc*32), at1);
    }
  }
  {
    float bv = bias[ntile*32 + l31];
    ushort_t* hrow = hDst + (ntile*32 + l31)*SHT;
    #pragma unroll
    for (int m=0;m<3;m++)
      #pragma unroll
      for (int g=0;g<4;g++) {
        float v0=acc[m][4*g+0]+bv; v0=v0>0.f?v0:0.f;
        float v1=acc[m][4*g+1]+bv; v1=v1>0.f?v1:0.f;
        float v2=acc[m][4*g+2]+bv; v2=v2>0.f?v2:0.f;
        float v3=acc[m][4*g+3]+bv; v3=v3>0.f?v3:0.f;
        uint2 pv; pv.x = pk2(v0,v1); pv.y = pk2(v2,v3);
        *(uint2*)(hrow + m*32 + 8*g + 4*h32) = pv;
      }
  }
  #pragma unroll
  for (int s=0;s<2;s++) {
    const f4v& a = s ? at1 : at0;
    float bv = bias[ntile*32 + s*16 + l15];
    float v0=a[0]+bv; v0=v0>0.f?v0:0.f;
    float v1=a[1]+bv; v1=v1>0.f?v1:0.f;
    float v2=a[2]+bv; v2=v2>0.f?v2:0.f;
    float v3=a[3]+bv; v3=v3>0.f?v3:0.f;
    uint2 pv; pv.x = pk2(v0,v1); pv.y = pk2(v2,v3);
    *(uint2*)(hDst + (ntile*32 + s*16 + l15)*SHT + 96 + 4*q4) = pv;
  }
}

// agg: aB[node][feat] = X . h, feat-tile `mt`, all nodes (3 tiles + tail).
__device__ __forceinline__ void agg_full(
    const ushort_t* hS, const ushort_t* Xs_, ushort_t* aDst, int mt, int lane)
{
  const int l31 = lane & 31, h32 = lane >> 5;
  const int l15 = lane & 15, q4 = lane >> 4;

  f16v acc[3];
  #pragma unroll
  for (int n=0;n<3;n++)
    #pragma unroll
    for (int r=0;r<16;r++) acc[n][r] = 0.f;
  const ushort_t* aP = hS + (mt*32 + l31)*SHT + h32*8;
  const ushort_t* bP = Xs_ + l31*SXS + h32*8;
  #pragma unroll
  for (int ks=0; ks<7; ks++) {              // K = 112 exact
    bf8v A = ld_frag(aP + ks*16);
    #pragma unroll
    for (int n=0;n<3;n++)
      acc[n] = MFMA32(A, ld_frag(bP + n*32*SXS + ks*16), acc[n]);
  }
  // node tail (rows 96..111), K padded to 128 (hT pad cols are zero)
  f4v at0 = (f4v){0.f,0.f,0.f,0.f}, at1 = (f4v){0.f,0.f,0.f,0.f};
  {
    const ushort_t* bT  = Xs_ + (96 + l15)*SXS + q4*8;
    const ushort_t* aT0 = hS + (mt*32 + l15)*SHT + q4*8;
    const ushort_t* aT1 = aT0 + 16*SHT;
    #pragma unroll
    for (int kc=0; kc<4; kc++) {
      bf8v Bt = ld_frag(bT + kc*32);
      at0 = MFMA16(ld_frag(aT0 + kc*32), Bt, at0);
      at1 = MFMA16(ld_frag(aT1 + kc*32), Bt, at1);
    }
  }
  #pragma unroll
  for (int n=0;n<3;n++) {
    ushort_t* arow = aDst + (n*32 + l31)*SAB;
    #pragma unroll
    for (int g=0;g<4;g++) {
      uint2 pv;
      pv.x = pk2(acc[n][4*g+0], acc[n][4*g+1]);
      pv.y = pk2(acc[n][4*g+2], acc[n][4*g+3]);
      *(uint2*)(arow + mt*32 + 8*g + 4*h32) = pv;
    }
  }
  {
    ushort_t* arow = aDst + (96 + l15)*SAB;
    #pragma unroll
    for (int s=0;s<2;s++) {
      const f4v& a = s ? at1 : at0;
      uint2 pv; pv.x = pk2(a[0],a[1]); pv.y = pk2(a[2],a[3]);
      *(uint2*)(arow + mt*32 + s*16 + 4*q4) = pv;
    }
  }
}

__global__ void prep_weights(const float* __restrict__ W1, const float* __restrict__ W2,
                             const float* __restrict__ W3, const float* __restrict__ W4,
                             ushort_t* __restrict__ o)
{
  int i = blockIdx.x*256 + threadIdx.x;
  if (i < 32768) {                       // W1p [256][128], K zero-padded
    int r = i >> 7, c = i & 127;
    o[i] = (c < NODE) ? f2bf(W1[r*NODE + c]) : (ushort_t)0;
  } else if (i < 98304) {                // W2 [256][256]
    o[i] = f2bf(W2[i - 32768]);
  } else if (i < 131072) {               // W3 [128][256]
    o[i] = f2bf(W3[i - 98304]);
  } else if (i < 139264) {               // W4 [64][128]
    o[i] = f2bf(W4[i - 131072]);
  }
}

__global__ void __launch_bounds__(512, 2) gcn_kernel(
    const float* __restrict__ x, const ushort_t* __restrict__ wsp,
    const float* __restrict__ b1, const float* __restrict__ b2,
    const float* __restrict__ b3, const float* __restrict__ b4,
    const float* __restrict__ W5, const float* __restrict__ b5,
    const float* __restrict__ Wf, const float* __restrict__ bfc,
    float* __restrict__ out)
{
  extern __shared__ ushort_t smem[];
  ushort_t* Xs = smem;
  ushort_t* hT = smem + HT_OFF;
  ushort_t* aB = smem + AB_OFF;

  const int tid  = threadIdx.x;
  const int w    = tid >> 6;
  const int lane = tid & 63;

  // zero K-pad cols 112..127 of Xs and hT (read by MFMA16 tails; proj/agg
  // never write cols >= 112, so one-time zeroing suffices)
  for (int i = tid; i < 112*4; i += 512) {
    int r = i >> 2, g = i & 3;
    *(uint2*)(Xs + r*SXS + 112 + g*4) = make_uint2(0u, 0u);
  }
  for (int i = tid; i < 256*4; i += 512) {
    int r = i >> 2, g = i & 3;
    *(uint2*)(hT + r*SHT + 112 + g*4) = make_uint2(0u, 0u);
  }
  // stage X: fp32 global -> bf16 LDS (b64 packed writes)
  {
    const float4* x4 = (const float4*)(x + (size_t)blockIdx.x * (NODE*NODE));
    for (int i = tid; i < (NODE*NODE/4); i += 512) {
      float4 v = x4[i];
      int r = i / 28, c4 = (i - r*28) * 4;
      uint2 pv; pv.x = pk2(v.x, v.y); pv.y = pk2(v.z, v.w);
      *(uint2*)(Xs + r*SXS + c4) = pv;
    }
  }
  __syncthreads();

  // [p1 + a2] fused: F=256, 8 waves, wave = feat-tile (same-wave handoff)
  proj_full<7,4,SXS>(Xs, wsp, 128, b1, hT, w, lane);
  agg_full(hT, Xs, aB, w, lane);
  __syncthreads();

  // [p2 + a3] fused: F=256, K=256
  proj_full<16,8,SAB>(aB, wsp + 32768, 256, b2, hT, w, lane);
  agg_full(hT, Xs, aB, w, lane);
  __syncthreads();

  // [p3 + a4] fused: F=128, K=256; waves 0..3
  if (w < 4) {
    proj_full<16,8,SAB>(aB, wsp + 98304, 256, b3, hT, w, lane);
    agg_full(hT, Xs, aB, w, lane);
  }
  __syncthreads();

  // [p4 + a5] fused: F=64, K=128; waves 0..1
  if (w < 2) {
    proj_full<8,4,SAB>(aB, wsp + 131072, 128, b4, hT, w, lane);
    agg_full(hT, Xs, aB, w, lane);
  }
  __syncthreads();

  // final: h5[n] = relu(b5 + a5[n][:].W5); out = bf + sum_n h5[n]*Wf[n]
  float partial = 0.f;
  if (tid < NODE) {
    const ushort_t* row = aB + tid*SAB;
    float s = 0.f;
    #pragma unroll
    for (int k4 = 0; k4 < 16; k4++) {
      uint2 u = *(const uint2*)(row + k4*4);
      s += bf2f((ushort_t)(u.x & 0xFFFF)) * W5[k4*4+0];
      s += bf2f((ushort_t)(u.x >> 16))    * W5[k4*4+1];
      s += bf2f((ushort_t)(u.y & 0xFFFF)) * W5[k4*4+2];
      s += bf2f((ushort_t)(u.y >> 16))    * W5[k4*4+3];
    }
    s += b5[0];
    s = s > 0.f ? s : 0.f;
    partial = s * Wf[tid];
  }
  float* red = (float*)Xs;               // Xs dead after a5
  if (tid < 128) red[tid] = partial;     // lanes 112..127 write 0
  __syncthreads();
  if (w == 0) {
    float v = red[lane] + red[lane + 64];
    #pragma unroll
    for (int off = 32; off > 0; off >>= 1)
      v += __shfl_xor(v, off, 64);
    if (lane == 0) out[blockIdx.x] = v + bfc[0];
  }
}

extern "C" void kernel_launch(void* const* d_in, const int* in_sizes, int n_in,
                              void* d_out, int out_size, void* d_ws, size_t ws_size,
                              hipStream_t stream) {
  const float* x   = (const float*)d_in[0];
  const float* W1  = (const float*)d_in[1];
  const float* b1  = (const float*)d_in[2];
  const float* W2  = (const float*)d_in[3];
  const float* b2  = (const float*)d_in[4];
  const float* W3  = (const float*)d_in[5];
  const float* b3  = (const float*)d_in[6];
  const float* W4  = (const float*)d_in[7];
  const float* b4  = (const float*)d_in[8];
  const float* W5  = (const float*)d_in[9];
  const float* b5  = (const float*)d_in[10];
  const float* Wf  = (const float*)d_in[11];
  const float* bfc = (const float*)d_in[12];
  ushort_t* wsp = (ushort_t*)d_ws;
  float* out = (float*)d_out;

  prep_weights<<<544, 256, 0, stream>>>(W1, W2, W3, W4, wsp);

  (void)hipFuncSetAttribute((const void*)gcn_kernel,
                            hipFuncAttributeMaxDynamicSharedMemorySize, SMEM_BYTES);
  gcn_kernel<<<NBATCH, 512, SMEM_BYTES, stream>>>(x, wsp, b1, b2, b3, b4,
                                                  W5, b5, Wf, bfc, out);
}